// Round 6
// baseline (461.838 us; speedup 1.0000x reference)
//
#include <hip/hip_runtime.h>

#define B_ 16
#define C_ 256
#define H_ 48
#define W_ 48
#define HW_ 2304

typedef float f4 __attribute__((ext_vector_type(4)));

// ws offsets in floats
#define WS_ZPART 0           // [16][256][9] = 36864   (dead after prep)
#define WS_FSPART 36864      // [4][16*2304] = 147456 -> 184320 (dead after prep)
#define WS_FSPAD 184320      // [16][54][56] = 48384 -> 232704  (dead after gca)
#define WS_MU 0              // [16][3][2304] = 110592 (reuses zpart region)
#define WS_RS 110592         // [16][3][2304] = 110592 -> 221184 (reuses fspart/fspad-dead)
#define WS_BASIS 232704      // 40*52 = 2080 -> 234784
#define WS_COEFFT 234784     // [16][3][256][16] = 196608 -> 431392
#define WS_MQ 431392         // [16][3][256] = 12288 -> 443680
#define WS_CMEAN 443680      // [16][3][16] = 768 -> 444448
#define WS_H 444448          // [3][16][64] = 3072 -> 447520
#define WS_G 447520          // [16][40][2304] = 1474560 -> 1922080 (7.69 MB)

__device__ __forceinline__ float wave_sum(float v) {
#pragma unroll
  for (int off = 32; off; off >>= 1) v += __shfl_xor(v, off, 64);
  return v;
}

// ---------- K1: fused single pass over feature: z partials + fs partials ----------
__global__ __launch_bounds__(256) void zfs1_kernel(const float* __restrict__ feat,
                                                   float* __restrict__ zpart,
                                                   float* __restrict__ fspart) {
  int b = blockIdx.x, cc = blockIdx.y, pc = blockIdx.z;
  int tid = threadIdx.x;
  int p = pc * 256 + tid;
  const float* f = feat + ((size_t)b * C_ + cc * 64) * HW_ + p;
  __shared__ float zsum[256];
  int w = tid >> 6, lane = tid & 63;
  float facc = 0.f;
#pragma unroll 8
  for (int j = 0; j < 64; ++j) {
    float v = f[(size_t)j * HW_];
    facc += v;
    float s = wave_sum(v);
    if (lane == 0) zsum[w * 64 + j] = s;
  }
  fspart[cc * (B_ * HW_) + b * HW_ + p] = facc;
  __syncthreads();
  if (tid < 64) {
    float zv = zsum[tid] + zsum[64 + tid] + zsum[128 + tid] + zsum[192 + tid];
    zpart[((size_t)b * 256 + cc * 64 + tid) * 9 + pc] = zv;
  }
}

// ---------- K2: prep, grid 104 blocks ----------
__global__ __launch_bounds__(256) void prep_kernel(
    const float* __restrict__ fspart, const float* __restrict__ zpart,
    const float* __restrict__ rw1, const float* __restrict__ rb1,
    const float* __restrict__ rw2, const float* __restrict__ rb2,
    const float* __restrict__ w1i, const float* __restrict__ b1i,
    const float* __restrict__ w1e, const float* __restrict__ b1e,
    const float* __restrict__ w1c, const float* __restrict__ b1c,
    float* __restrict__ fspad, float* __restrict__ basis,
    float* __restrict__ hout) {
  int bx = blockIdx.x, tid = threadIdx.x;
  if (bx < 16) {
    int b = bx;
    for (int i = tid; i < 54 * 56; i += 256) {
      int yy = i / 56;
      int xx = i - yy * 56;
      int y = yy - 3, x = xx - 3;
      float v = 0.f;
      if (y >= 0 && y < H_ && x >= 0 && x < W_) {
        int idx = b * HW_ + y * W_ + x;
        v = fspart[idx] + fspart[B_ * HW_ + idx] + fspart[2 * B_ * HW_ + idx] +
            fspart[3 * B_ * HW_ + idx];
      }
      fspad[b * 3024 + i] = v;
    }
    return;
  }
  if (bx < 56) {
    if (tid >= 64) return;
    int t = tid;
    float r = 0.f, th = 0.f;
    if (t < 49) {
      int iy = t / 7, ix = t - iy * 7;
      float gy = (float)iy - 3.f, gx = (float)ix - 3.f;
      r = sqrtf(gx * gx + gy * gy + 1e-8f);
      th = atan2f(gy, gx);
    }
    if (bx < 40) {
      int f = bx - 16;
      const float SIGL[3] = {4.f, 6.f, 8.f};
      const float SIGS[3] = {1.f, 2.f, 3.f};
      int i = (f < 8) ? f : f - 8;
      int c = i % 9, d = c / 3;
      float s = (f < 8) ? SIGL[c % 3] : SIGS[c % 3];
      float p = 0.f;
      if (t < 49) {
        float u = r / s;
        float g = expf(-0.5f * u * u);
        p = ((d == 0) ? 1.f : ((d == 1) ? u : (u * u - 1.f))) * g;
      }
      float ss = wave_sum(p * p);
      if (t < 49) basis[f * 52 + t] = p / sqrtf(ss + 1e-8f);
    } else if (t < 49) {
      int i = bx - 40;
      float r0 = rb2[0], r1 = rb2[1];
      for (int j = 0; j < 32; ++j) {
        float h = tanhf(r * rw1[j] + rb1[j]);
        r0 = fmaf(h, rw2[2 * j], r0);
        r1 = fmaf(h, rw2[2 * j + 1], r1);
      }
      int m = i >> 3, a = i & 7, o = (a >> 1) + 1;
      float ang = (a & 1) ? sinf((float)o * th) : cosf((float)o * th);
      basis[(24 + i) * 52 + t] = (m ? r1 : r0) * ang;
    }
    return;
  }
  // h MLP
  int idx = bx - 56;
  int branch = idx >> 4, b = idx & 15;
  const float* w1 = branch == 0 ? w1i : (branch == 1 ? w1e : w1c);
  const float* b1 = branch == 0 ? b1i : (branch == 1 ? b1e : b1c);
  __shared__ float zs[256], hp[256];
  {
    const float* zp = zpart + ((size_t)b * 256 + tid) * 9;
    float za = 0.f;
#pragma unroll
    for (int i = 0; i < 9; ++i) za += zp[i];
    zs[tid] = za * (1.f / (float)HW_);
  }
  __syncthreads();
  int j = tid & 63, part = tid >> 6;
  float acc = 0.f;
  const float* wp = w1 + part * 64 * 64 + j;
#pragma unroll
  for (int q = 0; q < 64; ++q) acc = fmaf(zs[part * 64 + q], wp[q * 64], acc);
  hp[tid] = acc;
  __syncthreads();
  if (tid < 64)
    hout[idx * 64 + tid] = fmaxf(
        b1[tid] + hp[tid] + hp[64 + tid] + hp[128 + tid] + hp[192 + tid], 0.f);
}

// ---------- K3: gca, grid 1216 = 640 coeffA blocks + 576 conv blocks ----------
__global__ __launch_bounds__(256) void gca_kernel(
    const float* __restrict__ fspad, const float* __restrict__ basis,
    const float* __restrict__ hbuf, const float* __restrict__ w2i,
    const float* __restrict__ b2i, const float* __restrict__ w2e,
    const float* __restrict__ b2e, const float* __restrict__ w2c,
    const float* __restrict__ b2c, float* __restrict__ G,
    float* __restrict__ coeffT) {
  int tid = threadIdx.x;
  if (blockIdx.x < 640) {  // coeffA: (b, ng)
    int j = blockIdx.x;
    int b = j / 40, ng = j - b * 40;
    int c = tid;
    int branch = (ng < 8) ? 0 : ((ng < 24) ? 1 : 2);
    int nl = ng - ((branch == 0) ? 0 : ((branch == 1) ? 8 : 24));
    int Nc = (branch == 0) ? 8 : 16;
    const float* w2 = branch == 0 ? w2i : (branch == 1 ? w2e : w2c);
    const float* b2 = branch == 0 ? b2i : (branch == 1 ? b2e : b2c);
    __shared__ float hs[64];
    if (c < 64) hs[c] = hbuf[(branch * 16 + b) * 64 + c];
    __syncthreads();
    float acc = b2[nl * 256 + c];
    const float* wp = w2 + (size_t)nl * 256 + c;
    size_t stride = (size_t)Nc * 256;
#pragma unroll
    for (int jj = 0; jj < 64; ++jj) acc = fmaf(hs[jj], wp[jj * stride], acc);
    float* ctp = coeffT + ((size_t)(b * 3 + branch) * 256 + c) * 16;
    ctp[nl] = acc;
    if (branch == 0) ctp[nl + 8] = 0.f;  // zero-pad inv branch to 16
    return;
  }
  // conv: window-in-registers, 10 basis rows per block, no LDS
  int i = blockIdx.x - 640;
  int ng = i / 144;
  int r = i - ng * 144;
  int b = r / 9, pc = r - b * 9;
  int p = pc * 256 + tid;
  int py = p / 48, px = p - py * 48;
  const float* wb = fspad + b * 3024 + py * 56 + px;
  float wreg[49];
#pragma unroll
  for (int dy = 0; dy < 7; ++dy)
#pragma unroll
    for (int dx = 0; dx < 7; ++dx) wreg[dy * 7 + dx] = wb[dy * 56 + dx];
  float* go = G + ((size_t)b * 40 + ng * 10) * HW_ + p;
#pragma unroll 2
  for (int ni = 0; ni < 10; ++ni) {
    const float* bs = basis + (ng * 10 + ni) * 52;  // uniform -> s_load
    float acc = 0.f;
#pragma unroll
    for (int k = 0; k < 49; ++k) acc = fmaf(bs[k], wreg[k], acc);
    go[(size_t)ni * HW_] = acc;
  }
}

// ---------- K4: per-(b,branch) Gram matrix M/256 and channel-mean ----------
__global__ __launch_bounds__(256) void mstat_kernel(
    const float* __restrict__ coeffT, float* __restrict__ Mq,
    float* __restrict__ cmean) {
  int b = blockIdx.x, branch = blockIdx.y, tid = threadIdx.x;
  __shared__ float Ls[4096];  // [256][16]
  const float* base = coeffT + (size_t)(b * 3 + branch) * 4096;
#pragma unroll
  for (int k = 0; k < 16; ++k) Ls[k * 256 + tid] = base[k * 256 + tid];
  __syncthreads();
  int nn = tid >> 4, mm = tid & 15;
  float dot = 0.f;
#pragma unroll 8
  for (int cc = 0; cc < 256; ++cc)
    dot = fmaf(Ls[((cc & 15) * 16 + (cc >> 4)) * 16 + nn],
               Ls[((cc & 15) * 16 + (cc >> 4)) * 16 + mm], dot);
  Mq[(b * 3 + branch) * 256 + tid] = dot * (1.f / 256.f);
  if (tid < 16) {
    float s = 0.f;
    for (int cc = 0; cc < 256; ++cc) s += Ls[cc * 16 + tid];
    cmean[(b * 3 + branch) * 16 + tid] = s * (1.f / 256.f);
  }
}

// ---------- K5: lnstat, grid (16, 3, 9), 256 thr: mu/rstd per (b,branch,p) ----------
__global__ __launch_bounds__(256) void lnstat_kernel(
    const float* __restrict__ G, const float* __restrict__ Mq,
    const float* __restrict__ cmean, float* __restrict__ mu_,
    float* __restrict__ rs_) {
  int b = blockIdx.x, branch = blockIdx.y, pc = blockIdx.z;
  int tid = threadIdx.x;
  __shared__ float Ms[256];
  __shared__ float cms[16];
  Ms[tid] = Mq[(b * 3 + branch) * 256 + tid];
  if (tid < 16) cms[tid] = cmean[(b * 3 + branch) * 16 + tid];
  __syncthreads();
  int p = pc * 256 + tid;
  int n0 = (branch == 0) ? 0 : ((branch == 1) ? 8 : 24);
  float gr[16];
#pragma unroll
  for (int n = 0; n < 16; ++n) gr[n] = G[((size_t)b * 40 + n0 + n) * HW_ + p];
  float mu = 0.f, q = 0.f;
#pragma unroll
  for (int n = 0; n < 16; ++n) {
    mu = fmaf(cms[n], gr[n], mu);
    float t = 0.f;
#pragma unroll
    for (int m = 0; m < 16; ++m) t = fmaf(Ms[n * 16 + m], gr[m], t);
    q = fmaf(gr[n], t, q);
  }
  mu_[(size_t)(b * 3 + branch) * HW_ + p] = mu;
  rs_[(size_t)(b * 3 + branch) * HW_ + p] = rsqrtf(q - mu * mu + 1e-5f);
}

// ---------- K6: pout, grid (16*8, 3), 256 thr ----------
// Block = (b, 32-channel chunk) x branch; wave = 8 channels x all 2304 p.
// Lane = position: every store is 64 lanes x 16 B = 1 KB contiguous; each
// channel's 9216 B row is written sequentially across the 9 pc iterations.
// No LDS, no syncs; stats preloaded from lnstat.
__global__ __launch_bounds__(256) void pout_kernel(
    const float* __restrict__ G, const float* __restrict__ coeffT,
    const float* __restrict__ mu_, const float* __restrict__ rs_,
    const float* __restrict__ g0, const float* __restrict__ be0,
    const float* __restrict__ g1, const float* __restrict__ be1,
    const float* __restrict__ g2, const float* __restrict__ be2,
    float* __restrict__ out) {
  int bx = blockIdx.x;
  int branch = blockIdx.y;
  int b = bx >> 3, cch = bx & 7;
  int tid = threadIdx.x;
  int wave = tid >> 6, lane = tid & 63;
  int c0 = cch * 32 + wave * 8;
  int n0 = (branch == 0) ? 0 : ((branch == 1) ? 8 : 24);
  const float* gp = (branch == 0) ? g0 : ((branch == 1) ? g1 : g2);
  const float* bp = (branch == 0) ? be0 : ((branch == 1) ? be1 : be2);
  float gch[8], bch[8];
#pragma unroll
  for (int i = 0; i < 8; ++i) {
    gch[i] = gp[c0 + i];
    bch[i] = bp[c0 + i];
  }
  const float* Gb = G + ((size_t)b * 40 + n0) * HW_;
  const float* ctb = coeffT + ((size_t)(b * 3 + branch) * 256 + c0) * 16;
  const float* mub = mu_ + (size_t)(b * 3 + branch) * HW_;
  const float* rsb = rs_ + (size_t)(b * 3 + branch) * HW_;
  float* ob = out + ((size_t)((branch * 16 + b) * 256 + c0)) * HW_;
#pragma unroll 1
  for (int pc = 0; pc < 9; ++pc) {
    int p = pc * 256 + lane * 4;
    f4 Gr[16];
#pragma unroll
    for (int n = 0; n < 16; ++n)
      Gr[n] = *reinterpret_cast<const f4*>(Gb + (size_t)n * HW_ + p);
    f4 mu4 = *reinterpret_cast<const f4*>(mub + p);
    f4 rs4 = *reinterpret_cast<const f4*>(rsb + p);
#pragma unroll
    for (int j = 0; j < 8; ++j) {
      const f4* ct4 = reinterpret_cast<const f4*>(ctb + j * 16);
      f4 a = ct4[0], bb = ct4[1], cc = ct4[2], dd = ct4[3];
      f4 v = a.x * Gr[0];
      v += a.y * Gr[1];
      v += a.z * Gr[2];
      v += a.w * Gr[3];
      v += bb.x * Gr[4];
      v += bb.y * Gr[5];
      v += bb.z * Gr[6];
      v += bb.w * Gr[7];
      v += cc.x * Gr[8];
      v += cc.y * Gr[9];
      v += cc.z * Gr[10];
      v += cc.w * Gr[11];
      v += dd.x * Gr[12];
      v += dd.y * Gr[13];
      v += dd.z * Gr[14];
      v += dd.w * Gr[15];
      f4 o = (v - mu4) * rs4 * gch[j] + bch[j];
      __builtin_nontemporal_store(o,
                                  reinterpret_cast<f4*>(ob + (size_t)j * HW_ + p));
    }
  }
}

extern "C" void kernel_launch(void* const* d_in, const int* in_sizes, int n_in,
                              void* d_out, int out_size, void* d_ws,
                              size_t ws_size, hipStream_t stream) {
  const float* feat = (const float*)d_in[0];
  float* ws = (float*)d_ws;
  float* zpart = ws + WS_ZPART;
  float* fspart = ws + WS_FSPART;
  float* fspad = ws + WS_FSPAD;
  float* mu_ = ws + WS_MU;   // overlaps dead zpart region
  float* rs_ = ws + WS_RS;   // overlaps dead fspart/fspad region
  float* basis = ws + WS_BASIS;
  float* coeffT = ws + WS_COEFFT;
  float* Mq = ws + WS_MQ;
  float* cmean = ws + WS_CMEAN;
  float* hbuf = ws + WS_H;
  float* G = ws + WS_G;

  zfs1_kernel<<<dim3(16, 4, 9), 256, 0, stream>>>(feat, zpart, fspart);
  prep_kernel<<<104, 256, 0, stream>>>(
      fspart, zpart, (const float*)d_in[13], (const float*)d_in[14],
      (const float*)d_in[15], (const float*)d_in[16], (const float*)d_in[1],
      (const float*)d_in[2], (const float*)d_in[5], (const float*)d_in[6],
      (const float*)d_in[9], (const float*)d_in[10], fspad, basis, hbuf);
  gca_kernel<<<1216, 256, 0, stream>>>(
      fspad, basis, hbuf, (const float*)d_in[3], (const float*)d_in[4],
      (const float*)d_in[7], (const float*)d_in[8], (const float*)d_in[11],
      (const float*)d_in[12], G, coeffT);
  mstat_kernel<<<dim3(16, 3), 256, 0, stream>>>(coeffT, Mq, cmean);
  lnstat_kernel<<<dim3(16, 3, 9), 256, 0, stream>>>(G, Mq, cmean, mu_, rs_);
  pout_kernel<<<dim3(16 * 8, 3), 256, 0, stream>>>(
      G, coeffT, mu_, rs_, (const float*)d_in[17], (const float*)d_in[18],
      (const float*)d_in[19], (const float*)d_in[20], (const float*)d_in[21],
      (const float*)d_in[22], (float*)d_out);
}

// Round 7
// 248.773 us; speedup vs baseline: 1.8565x; 1.8565x over previous
//
#include <hip/hip_runtime.h>

#define B_ 16
#define C_ 256
#define H_ 48
#define W_ 48
#define HW_ 2304

typedef float f4 __attribute__((ext_vector_type(4)));

// ws offsets in floats
#define WS_ZPART 0           // [16][256][9] = 36864   (dead after prep)
#define WS_FSPART 36864      // [4][16*2304] = 147456 -> 184320 (dead after prep)
#define WS_FSPAD 184320      // [16][54][56] = 48384 -> 232704  (dead after gca)
#define WS_MU 0              // [16][3][2304] = 110592 (reuses dead zpart/fspart)
#define WS_RS 110592         // [16][3][2304] -> 221184 (reuses dead fspart/fspad)
#define WS_BASIS 232704      // 40*52 = 2080 -> 234784
#define WS_COEFFT 234784     // [16][3][256][16] = 196608 -> 431392
#define WS_H 444448          // [3][16][64] = 3072 -> 447520
#define WS_G 447520          // [16][40][2304] = 1474560 -> 1922080 (7.69 MB)

__device__ __forceinline__ float wave_sum(float v) {
#pragma unroll
  for (int off = 32; off; off >>= 1) v += __shfl_xor(v, off, 64);
  return v;
}

// ---------- K1: fused single pass over feature: z partials + fs partials ----------
__global__ __launch_bounds__(256) void zfs1_kernel(const float* __restrict__ feat,
                                                   float* __restrict__ zpart,
                                                   float* __restrict__ fspart) {
  int b = blockIdx.x, cc = blockIdx.y, pc = blockIdx.z;
  int tid = threadIdx.x;
  int p = pc * 256 + tid;
  const float* f = feat + ((size_t)b * C_ + cc * 64) * HW_ + p;
  __shared__ float zsum[256];
  int w = tid >> 6, lane = tid & 63;
  float facc = 0.f;
#pragma unroll 8
  for (int j = 0; j < 64; ++j) {
    float v = f[(size_t)j * HW_];
    facc += v;
    float s = wave_sum(v);
    if (lane == 0) zsum[w * 64 + j] = s;
  }
  fspart[cc * (B_ * HW_) + b * HW_ + p] = facc;
  __syncthreads();
  if (tid < 64) {
    float zv = zsum[tid] + zsum[64 + tid] + zsum[128 + tid] + zsum[192 + tid];
    zpart[((size_t)b * 256 + cc * 64 + tid) * 9 + pc] = zv;
  }
}

// ---------- K2: prep, grid 104 blocks ----------
__global__ __launch_bounds__(256) void prep_kernel(
    const float* __restrict__ fspart, const float* __restrict__ zpart,
    const float* __restrict__ rw1, const float* __restrict__ rb1,
    const float* __restrict__ rw2, const float* __restrict__ rb2,
    const float* __restrict__ w1i, const float* __restrict__ b1i,
    const float* __restrict__ w1e, const float* __restrict__ b1e,
    const float* __restrict__ w1c, const float* __restrict__ b1c,
    float* __restrict__ fspad, float* __restrict__ basis,
    float* __restrict__ hout) {
  int bx = blockIdx.x, tid = threadIdx.x;
  if (bx < 16) {
    int b = bx;
    for (int i = tid; i < 54 * 56; i += 256) {
      int yy = i / 56;
      int xx = i - yy * 56;
      int y = yy - 3, x = xx - 3;
      float v = 0.f;
      if (y >= 0 && y < H_ && x >= 0 && x < W_) {
        int idx = b * HW_ + y * W_ + x;
        v = fspart[idx] + fspart[B_ * HW_ + idx] + fspart[2 * B_ * HW_ + idx] +
            fspart[3 * B_ * HW_ + idx];
      }
      fspad[b * 3024 + i] = v;
    }
    return;
  }
  if (bx < 56) {
    if (tid >= 64) return;
    int t = tid;
    float r = 0.f, th = 0.f;
    if (t < 49) {
      int iy = t / 7, ix = t - iy * 7;
      float gy = (float)iy - 3.f, gx = (float)ix - 3.f;
      r = sqrtf(gx * gx + gy * gy + 1e-8f);
      th = atan2f(gy, gx);
    }
    if (bx < 40) {
      int f = bx - 16;
      const float SIGL[3] = {4.f, 6.f, 8.f};
      const float SIGS[3] = {1.f, 2.f, 3.f};
      int i = (f < 8) ? f : f - 8;
      int c = i % 9, d = c / 3;
      float s = (f < 8) ? SIGL[c % 3] : SIGS[c % 3];
      float p = 0.f;
      if (t < 49) {
        float u = r / s;
        float g = expf(-0.5f * u * u);
        p = ((d == 0) ? 1.f : ((d == 1) ? u : (u * u - 1.f))) * g;
      }
      float ss = wave_sum(p * p);
      if (t < 49) basis[f * 52 + t] = p / sqrtf(ss + 1e-8f);
    } else if (t < 49) {
      int i = bx - 40;
      float r0 = rb2[0], r1 = rb2[1];
      for (int j = 0; j < 32; ++j) {
        float h = tanhf(r * rw1[j] + rb1[j]);
        r0 = fmaf(h, rw2[2 * j], r0);
        r1 = fmaf(h, rw2[2 * j + 1], r1);
      }
      int m = i >> 3, a = i & 7, o = (a >> 1) + 1;
      float ang = (a & 1) ? sinf((float)o * th) : cosf((float)o * th);
      basis[(24 + i) * 52 + t] = (m ? r1 : r0) * ang;
    }
    return;
  }
  // h MLP
  int idx = bx - 56;
  int branch = idx >> 4, b = idx & 15;
  const float* w1 = branch == 0 ? w1i : (branch == 1 ? w1e : w1c);
  const float* b1 = branch == 0 ? b1i : (branch == 1 ? b1e : b1c);
  __shared__ float zs[256], hp[256];
  {
    const float* zp = zpart + ((size_t)b * 256 + tid) * 9;
    float za = 0.f;
#pragma unroll
    for (int i = 0; i < 9; ++i) za += zp[i];
    zs[tid] = za * (1.f / (float)HW_);
  }
  __syncthreads();
  int j = tid & 63, part = tid >> 6;
  float acc = 0.f;
  const float* wp = w1 + part * 64 * 64 + j;
#pragma unroll
  for (int q = 0; q < 64; ++q) acc = fmaf(zs[part * 64 + q], wp[q * 64], acc);
  hp[tid] = acc;
  __syncthreads();
  if (tid < 64)
    hout[idx * 64 + tid] = fmaxf(
        b1[tid] + hp[tid] + hp[64 + tid] + hp[128 + tid] + hp[192 + tid], 0.f);
}

// ---------- K3: gca, grid 1216 = 640 coeffA blocks + 576 conv blocks ----------
__global__ __launch_bounds__(256) void gca_kernel(
    const float* __restrict__ fspad, const float* __restrict__ basis,
    const float* __restrict__ hbuf, const float* __restrict__ w2i,
    const float* __restrict__ b2i, const float* __restrict__ w2e,
    const float* __restrict__ b2e, const float* __restrict__ w2c,
    const float* __restrict__ b2c, float* __restrict__ G,
    float* __restrict__ coeffT) {
  int tid = threadIdx.x;
  if (blockIdx.x < 640) {  // coeffA: (b, ng)
    int j = blockIdx.x;
    int b = j / 40, ng = j - b * 40;
    int c = tid;
    int branch = (ng < 8) ? 0 : ((ng < 24) ? 1 : 2);
    int nl = ng - ((branch == 0) ? 0 : ((branch == 1) ? 8 : 24));
    int Nc = (branch == 0) ? 8 : 16;
    const float* w2 = branch == 0 ? w2i : (branch == 1 ? w2e : w2c);
    const float* b2 = branch == 0 ? b2i : (branch == 1 ? b2e : b2c);
    __shared__ float hs[64];
    if (c < 64) hs[c] = hbuf[(branch * 16 + b) * 64 + c];
    __syncthreads();
    float acc = b2[nl * 256 + c];
    const float* wp = w2 + (size_t)nl * 256 + c;
    size_t stride = (size_t)Nc * 256;
#pragma unroll
    for (int jj = 0; jj < 64; ++jj) acc = fmaf(hs[jj], wp[jj * stride], acc);
    float* ctp = coeffT + ((size_t)(b * 3 + branch) * 256 + c) * 16;
    ctp[nl] = acc;
    if (branch == 0) ctp[nl + 8] = 0.f;  // zero-pad inv branch to 16
    return;
  }
  // conv: window-in-registers, 10 basis rows per block, no LDS
  int i = blockIdx.x - 640;
  int ng = i / 144;
  int r = i - ng * 144;
  int b = r / 9, pc = r - b * 9;
  int p = pc * 256 + tid;
  int py = p / 48, px = p - py * 48;
  const float* wb = fspad + b * 3024 + py * 56 + px;
  float wreg[49];
#pragma unroll
  for (int dy = 0; dy < 7; ++dy)
#pragma unroll
    for (int dx = 0; dx < 7; ++dx) wreg[dy * 7 + dx] = wb[dy * 56 + dx];
  float* go = G + ((size_t)b * 40 + ng * 10) * HW_ + p;
#pragma unroll 2
  for (int ni = 0; ni < 10; ++ni) {
    const float* bs = basis + (ng * 10 + ni) * 52;  // uniform -> s_load
    float acc = 0.f;
#pragma unroll
    for (int k = 0; k < 49; ++k) acc = fmaf(bs[k], wreg[k], acc);
    go[(size_t)ni * HW_] = acc;
  }
}

// ---------- K4: stat, grid (16, 3, 9), 256 thr ----------
// Per block: recompute 16x16 Gram + cmean from coeffT (cheap, deterministic),
// then mu/rstd for its 256 positions via the Gram trick.
__global__ __launch_bounds__(256) void stat_kernel(
    const float* __restrict__ G, const float* __restrict__ coeffT,
    float* __restrict__ mu_, float* __restrict__ rs_) {
  int b = blockIdx.x, branch = blockIdx.y, pc = blockIdx.z;
  int tid = threadIdx.x;
  __shared__ float Ls[4096];  // [256 c][16 n]
  __shared__ float Ms[256];
  __shared__ float cms[16];
  const float* base = coeffT + (size_t)(b * 3 + branch) * 4096;
#pragma unroll
  for (int k = 0; k < 16; ++k) Ls[k * 256 + tid] = base[k * 256 + tid];
  __syncthreads();
  int nn = tid >> 4, mm = tid & 15;
  float dot = 0.f;
#pragma unroll 8
  for (int cc = 0; cc < 256; ++cc)
    dot = fmaf(Ls[cc * 16 + nn], Ls[cc * 16 + mm], dot);
  Ms[tid] = dot * (1.f / 256.f);
  if (tid < 16) {
    float s = 0.f;
    for (int cc = 0; cc < 256; ++cc) s += Ls[cc * 16 + tid];
    cms[tid] = s * (1.f / 256.f);
  }
  __syncthreads();
  int p = pc * 256 + tid;
  int n0 = (branch == 0) ? 0 : ((branch == 1) ? 8 : 24);
  float gr[16];
#pragma unroll
  for (int n = 0; n < 16; ++n) gr[n] = G[((size_t)b * 40 + n0 + n) * HW_ + p];
  float mu = 0.f, q = 0.f;
#pragma unroll
  for (int n = 0; n < 16; ++n) {
    mu = fmaf(cms[n], gr[n], mu);
    float t = 0.f;
#pragma unroll
    for (int m = 0; m < 16; ++m) t = fmaf(Ms[n * 16 + m], gr[m], t);
    q = fmaf(gr[n], t, q);
  }
  mu_[(size_t)(b * 3 + branch) * HW_ + p] = mu;
  rs_[(size_t)(b * 3 + branch) * HW_ + p] = rsqrtf(q - mu * mu + 1e-5f);
}

// ---------- K5: pout, grid (16*36, 3), 256 thr ----------
// Block = (b, 64-ch quarter, 256-pos chunk); wave = 16 ch x 256 p.
// Lane = position: every store is 64 lanes x 16 B = 1 KB contiguous.
// coeffT slice staged once in 4 KB LDS (broadcast reads); no prologue stats.
// 1728 blocks = 6912 waves = 27 waves/CU (the R6 failure was 6 waves/CU).
__global__ __launch_bounds__(256) void pout_kernel(
    const float* __restrict__ G, const float* __restrict__ coeffT,
    const float* __restrict__ mu_, const float* __restrict__ rs_,
    const float* __restrict__ g0, const float* __restrict__ be0,
    const float* __restrict__ g1, const float* __restrict__ be1,
    const float* __restrict__ g2, const float* __restrict__ be2,
    float* __restrict__ out) {
  int branch = blockIdx.y;
  int bx = blockIdx.x;
  int b = bx / 36;
  int r = bx - b * 36;
  int cq = r / 9, pc = r - cq * 9;
  int tid = threadIdx.x;
  int wave = tid >> 6, lane = tid & 63;
  int c0 = cq * 64 + wave * 16;
  int p = pc * 256 + lane * 4;
  int n0 = (branch == 0) ? 0 : ((branch == 1) ? 8 : 24);
  __shared__ __align__(16) float ctS[1024];  // [64 ch][16 n]
  {
    const float* cts = coeffT + ((size_t)(b * 3 + branch) * 256 + cq * 64) * 16;
    reinterpret_cast<f4*>(ctS)[tid] = reinterpret_cast<const f4*>(cts)[tid];
  }
  const float* Gb = G + ((size_t)b * 40 + n0) * HW_ + p;
  f4 Gr[16];
#pragma unroll
  for (int n = 0; n < 16; ++n)
    Gr[n] = *reinterpret_cast<const f4*>(Gb + (size_t)n * HW_);
  f4 mu4 = *reinterpret_cast<const f4*>(mu_ + (size_t)(b * 3 + branch) * HW_ + p);
  f4 rs4 = *reinterpret_cast<const f4*>(rs_ + (size_t)(b * 3 + branch) * HW_ + p);
  const float* gp = (branch == 0) ? g0 : ((branch == 1) ? g1 : g2);
  const float* bp = (branch == 0) ? be0 : ((branch == 1) ? be1 : be2);
  __syncthreads();
  float* ob = out + ((size_t)((branch * 16 + b) * 256 + c0)) * HW_ + p;
#pragma unroll 4
  for (int j = 0; j < 16; ++j) {
    const f4* ct4 = reinterpret_cast<const f4*>(ctS + (wave * 16 + j) * 16);
    f4 a = ct4[0], bb = ct4[1], cc = ct4[2], dd = ct4[3];
    f4 v = a.x * Gr[0];
    v += a.y * Gr[1];
    v += a.z * Gr[2];
    v += a.w * Gr[3];
    v += bb.x * Gr[4];
    v += bb.y * Gr[5];
    v += bb.z * Gr[6];
    v += bb.w * Gr[7];
    v += cc.x * Gr[8];
    v += cc.y * Gr[9];
    v += cc.z * Gr[10];
    v += cc.w * Gr[11];
    v += dd.x * Gr[12];
    v += dd.y * Gr[13];
    v += dd.z * Gr[14];
    v += dd.w * Gr[15];
    f4 o = (v - mu4) * rs4 * gp[c0 + j] + bp[c0 + j];
    __builtin_nontemporal_store(o,
                                reinterpret_cast<f4*>(ob + (size_t)j * HW_));
  }
}

extern "C" void kernel_launch(void* const* d_in, const int* in_sizes, int n_in,
                              void* d_out, int out_size, void* d_ws,
                              size_t ws_size, hipStream_t stream) {
  const float* feat = (const float*)d_in[0];
  float* ws = (float*)d_ws;
  float* zpart = ws + WS_ZPART;
  float* fspart = ws + WS_FSPART;
  float* fspad = ws + WS_FSPAD;
  float* mu_ = ws + WS_MU;  // overlaps dead zpart/fspart region
  float* rs_ = ws + WS_RS;  // overlaps dead fspart/fspad region
  float* basis = ws + WS_BASIS;
  float* coeffT = ws + WS_COEFFT;
  float* hbuf = ws + WS_H;
  float* G = ws + WS_G;

  zfs1_kernel<<<dim3(16, 4, 9), 256, 0, stream>>>(feat, zpart, fspart);
  prep_kernel<<<104, 256, 0, stream>>>(
      fspart, zpart, (const float*)d_in[13], (const float*)d_in[14],
      (const float*)d_in[15], (const float*)d_in[16], (const float*)d_in[1],
      (const float*)d_in[2], (const float*)d_in[5], (const float*)d_in[6],
      (const float*)d_in[9], (const float*)d_in[10], fspad, basis, hbuf);
  gca_kernel<<<1216, 256, 0, stream>>>(
      fspad, basis, hbuf, (const float*)d_in[3], (const float*)d_in[4],
      (const float*)d_in[7], (const float*)d_in[8], (const float*)d_in[11],
      (const float*)d_in[12], G, coeffT);
  stat_kernel<<<dim3(16, 3, 9), 256, 0, stream>>>(G, coeffT, mu_, rs_);
  pout_kernel<<<dim3(16 * 36, 3), 256, 0, stream>>>(
      G, coeffT, mu_, rs_, (const float*)d_in[17], (const float*)d_in[18],
      (const float*)d_in[19], (const float*)d_in[20], (const float*)d_in[21],
      (const float*)d_in[22], (float*)d_out);
}